// Round 9
// baseline (10594.984 us; speedup 1.0000x reference)
//
#include <hip/hip_runtime.h>
#include <math.h>

#define Bq   16
#define Tq   1024
#define OUTq 64
#define Hq   512
#define Nq   128
#define Mq   40
#define NT   512
#define NISL 16        // islands = batches
#define GWG  13        // gate WGs per pair (12 x 40 dims + 1 x 32 dims)
#define IWG  14        // WGs per pair (GWG + 1 mem)
#define NWG  112       // 8 pairs x 14 WGs; pair p serves islands p and p+8
#define EPSq 1e-8f
#define MAGIC 0x00C0FFEEu

typedef unsigned long long ull;

__device__ __forceinline__ float sigmf(float x){ return 1.f/(1.f + expf(-x)); }
__device__ __forceinline__ float softplusf(float x){ return (x > 20.f) ? x : log1pf(expf(x)); }

// Agent-scope atomic ops: authoritative cross-XCD path.
__device__ __forceinline__ ull icld64(const ull* p){
  return __hip_atomic_load(p, __ATOMIC_RELAXED, __HIP_MEMORY_SCOPE_AGENT);
}
__device__ __forceinline__ void icst64(ull* p, ull v){
  __hip_atomic_store(p, v, __ATOMIC_RELAXED, __HIP_MEMORY_SCOPE_AGENT);
}
// IC poll load: sc0 bypasses L1, sc1 bypasses L2 -> reads the coherence point
// like the agent atomic load, but as a PLAIN coalescing load.
__device__ __forceinline__ ull icpoll64(const ull* p){
  ull v;
  asm volatile("global_load_dwordx2 %0, %1, off sc0 sc1\n\ts_waitcnt vmcnt(0)"
               : "=v"(v) : "v"(p) : "memory");
  return v;
}
__device__ __forceinline__ ull packtv(unsigned tag, float v){
  return ((ull)tag << 32) | (ull)__float_as_uint(v);
}
__device__ __forceinline__ float lowf(ull v){ return __uint_as_float((unsigned)v); }

// Tag-verified wait (tag+payload one atomic 8B word, tags monotone, parity-2
// slot reuse guarded by the dependency chain). `fast` enabled only after the
// runtime handshake proved sc0sc1 loads observe agent stores; bounded with an
// agent-loop tail so no configuration can hang. (r7 lesson: per-word spin —
// detect+data in ONE load — beats counter-gated transport by ~2 RTTs/hop.)
__device__ __forceinline__ float waitword(const ull* sh, unsigned want, bool fast){
  if (fast){
    #pragma unroll 1
    for (int i = 0; i < 4096; ++i){
      const ull v = icpoll64(sh);
      if ((unsigned)(v >> 32) == want) return lowf(v);
      __builtin_amdgcn_s_sleep(1);
    }
  }
  #pragma unroll 1
  for (;;){
    const ull v = icld64(sh);
    if ((unsigned)(v >> 32) == want) return lowf(v);
    __builtin_amdgcn_s_sleep(1);
  }
}

__device__ __forceinline__ int ready_and_handshake(ull* rdy, ull* magic, int blk){
  __hip_atomic_fetch_add(rdy, 1ull, __ATOMIC_RELAXED, __HIP_MEMORY_SCOPE_AGENT);
  while (icld64(rdy) < (ull)NWG) __builtin_amdgcn_s_sleep(8);
  if (blk == 0) icst64(magic, ((ull)MAGIC << 32) | 1ull);
  #pragma unroll 1
  for (int i = 0; i < 4000; ++i){
    if ((unsigned)(icpoll64(magic) >> 32) == MAGIC) return 1;
    __builtin_amdgcn_s_sleep(2);
  }
  return 0;
}

// Dual-island WGs (r9): weights are SHARED across batches, so one WG-set
// serves islands b and b+8 — every streamed weight byte feeds 2 island-steps,
// and the two islands' publish/detect latencies overlap (parallel thread-split
// waits + parallel wave0/wave1 serial sections). Comm protocol identical to
// the proven r4 kernel.
extern "C" __global__ void __launch_bounds__(NT, 1)
ntm_kernel(const float* __restrict__ xg,  const float* __restrict__ h0g,
           const float* __restrict__ c0g, const float* __restrict__ mem0g,
           const float* __restrict__ read0g,
           const float* __restrict__ Wih, const float* __restrict__ bih,
           const float* __restrict__ Whh, const float* __restrict__ bhh,
           const float* __restrict__ Wfc, const float* __restrict__ bfc,
           const float* __restrict__ We,  const float* __restrict__ be,
           const float* __restrict__ Wa,  const float* __restrict__ ba,
           const float* __restrict__ Wk,  const float* __restrict__ bk,
           const float* __restrict__ Wb,  const float* __restrict__ bbeta,
           float* __restrict__ yout, ull* __restrict__ rdy,
           ull* __restrict__ h_sh, ull* __restrict__ r_sh)
{
  const int blk = blockIdx.x;
  const int tid = threadIdx.x;
  const int pr  = blk & 7;           // pair id (XCD under %8 round-robin)
  const int j   = blk >> 3;          // 0..13 within pair
  const int batA = pr, batB = pr + 8;
  const int slot = j;
  __shared__ __align__(16) char smem[62720];
  __shared__ int s_fast;
  ull* magic = rdy + 1;

  if (slot < GWG){
    // ---- gate WG: islands A,B; h-dims [d0, d0+nd) (all 4 gates) ----
    float* inp_sA = (float*)smem;               // 640 f
    float* inp_sB = (float*)(smem + 2560);      // 640 f
    float* red_sA = (float*)(smem + 5120);      // 160 x 17
    float* red_sB = (float*)(smem + 16000);     // 160 x 17
    float* rw_s   = (float*)(smem + 26880);     // 160 x 41 (shared weights)
    float* r_sA   = (float*)(smem + 53120);     // 40
    float* r_sB   = (float*)(smem + 53280);     // 40
    float* gate_sA= (float*)(smem + 53440);     // 160
    float* gate_sB= (float*)(smem + 54080);     // 160
    float* c_sA   = (float*)(smem + 54720);     // 40
    float* c_sB   = (float*)(smem + 54880);     // 40
    float* bias_s = (float*)(smem + 55040);     // 160 (shared)

    const int kseg  = tid & 15;
    const int rslot = tid >> 4;
    const int nd    = (slot < 12) ? 40 : 32;
    const int d0    = slot * 40;
    const int rowsR = 4 * nd;

    float4 w4[5][9];
    #pragma unroll
    for (int rr = 0; rr < 5; ++rr){
      const int row = rslot*5 + rr;
      if (row < rowsR){
        const int gate = row / nd, ld = row - gate*nd;
        const int grow = gate*Hq + d0 + ld;
        #pragma unroll
        for (int kk = 0; kk < 9; ++kk){
          float v[4];
          #pragma unroll
          for (int c4 = 0; c4 < 4; ++c4){
            const int k = kseg*36 + kk*4 + c4;
            v[c4] = (k < 64) ? Wih[grow*104 + k] : Whh[grow*512 + (k - 64)];
          }
          w4[rr][kk] = make_float4(v[0], v[1], v[2], v[3]);
        }
      } else {
        #pragma unroll
        for (int kk = 0; kk < 9; ++kk) w4[rr][kk] = make_float4(0.f,0.f,0.f,0.f);
      }
    }
    if (tid < rowsR){
      const int gate = tid / nd, ld = tid - gate*nd;
      const int grow = gate*Hq + d0 + ld;
      bias_s[tid] = bih[grow] + bhh[grow];
    }
    for (int i = tid; i < rowsR*40; i += NT){
      const int row = i / 40, m = i - row*40;
      const int gate = row / nd, ld = row - gate*nd;
      const int grow = gate*Hq + d0 + ld;
      rw_s[row*41 + m] = Wih[grow*104 + 64 + m];
    }
    if (tid < nd){
      c_sA[tid] = c0g[batA*Hq + d0 + tid];
      c_sB[tid] = c0g[batB*Hq + d0 + tid];
    }
    if (tid < 16)
      *(float4*)&inp_sA[tid*4] = ((const float4*)xg)[(batA*Tq + 0)*16 + tid];
    else if (tid < 32)
      *(float4*)&inp_sB[(tid-16)*4] = ((const float4*)xg)[(batB*Tq + 0)*16 + tid-16];
    if (tid < 128)
      *(float4*)&inp_sA[64 + tid*4] = ((const float4*)h0g)[batA*128 + tid];
    else if (tid < 256)
      *(float4*)&inp_sB[64 + (tid-128)*4] = ((const float4*)h0g)[batB*128 + (tid-128)];
    __syncthreads();
    if (tid == 0) s_fast = ready_and_handshake(rdy, magic, blk);
    __syncthreads();
    const bool fast = (s_fast != 0);

    for (int t = 0; t < Tq; ++t){
      const int p = t & 1, pm = (t - 1) & 1;
      // main GEMV island A then B — SAME w4 registers/stream serve both
      {
        float acc[5] = {0.f,0.f,0.f,0.f,0.f};
        const float* bp = inp_sA + kseg*36;
        #pragma unroll
        for (int kk = 0; kk < 9; ++kk){
          const float4 f = *(const float4*)&bp[kk*4];
          #pragma unroll
          for (int rr = 0; rr < 5; ++rr)
            acc[rr] += w4[rr][kk].x*f.x + w4[rr][kk].y*f.y
                     + w4[rr][kk].z*f.z + w4[rr][kk].w*f.w;
        }
        #pragma unroll
        for (int rr = 0; rr < 5; ++rr)
          red_sA[(rslot*5 + rr)*17 + kseg] = acc[rr];
      }
      {
        float acc[5] = {0.f,0.f,0.f,0.f,0.f};
        const float* bp = inp_sB + kseg*36;
        #pragma unroll
        for (int kk = 0; kk < 9; ++kk){
          const float4 f = *(const float4*)&bp[kk*4];
          #pragma unroll
          for (int rr = 0; rr < 5; ++rr)
            acc[rr] += w4[rr][kk].x*f.x + w4[rr][kk].y*f.y
                     + w4[rr][kk].z*f.z + w4[rr][kk].w*f.w;
        }
        #pragma unroll
        for (int rr = 0; rr < 5; ++rr)
          red_sB[(rslot*5 + rr)*17 + kseg] = acc[rr];
      }
      // r(t-1): parallel thread-split waits (A: lanes 0..39, B: 64..103)
      if (t == 0){
        if (tid < 40) r_sA[tid] = read0g[batA*Mq + tid];
        else if (tid >= 64 && tid < 104) r_sB[tid-64] = read0g[batB*Mq + (tid-64)];
      } else {
        if (tid < 40)
          r_sA[tid] = waitword(&r_sh[(pm*NISL + batA)*Mq + tid], (unsigned)t, fast);
        else if (tid >= 64 && tid < 104)
          r_sB[tid-64] = waitword(&r_sh[(pm*NISL + batB)*Mq + (tid-64)], (unsigned)t, fast);
      }
      __syncthreads();                 // S1
      // phase2: A by tid<rowsR, B by 256<=tid<256+rowsR (parallel)
      if (tid < rowsR){
        float s2 = bias_s[tid];
        const float* rp = &red_sA[tid*17];
        #pragma unroll
        for (int q = 0; q < 16; ++q) s2 += rp[q];
        const float* rwp = &rw_s[tid*41];
        #pragma unroll
        for (int m = 0; m < 40; ++m) s2 += rwp[m]*r_sA[m];
        gate_sA[tid] = s2;
      } else if (tid >= 256 && tid < 256 + rowsR){
        const int row = tid - 256;
        float s2 = bias_s[row];
        const float* rp = &red_sB[row*17];
        #pragma unroll
        for (int q = 0; q < 16; ++q) s2 += rp[q];
        const float* rwp = &rw_s[row*41];
        #pragma unroll
        for (int m = 0; m < 40; ++m) s2 += rwp[m]*r_sB[m];
        gate_sB[row] = s2;
      }
      __syncthreads();                 // S2
      // nonlin + publish: A lanes 0..nd, B lanes 64..64+nd (parallel waves)
      if (tid < nd){
        const float gi = gate_sA[tid];
        const float gf = gate_sA[nd + tid];
        const float gc = gate_sA[2*nd + tid];
        const float go = gate_sA[3*nd + tid];
        const float iv = sigmf(gi), fv = sigmf(gf), gv = tanhf(gc), ov = sigmf(go);
        const float cn = fv*c_sA[tid] + iv*gv;
        const float hn = ov*tanhf(cn);
        c_sA[tid] = cn;
        icst64(&h_sh[(p*NISL + batA)*Hq + d0 + tid], packtv((unsigned)(t+1), hn));
        if (t == Tq - 1){
          yout[Bq*Tq*OUTq + batA*Hq + d0 + tid] = hn;
          yout[Bq*Tq*OUTq + Bq*Hq + batA*Hq + d0 + tid] = cn;
        }
      } else if (tid >= 64 && tid < 64 + nd){
        const int ld = tid - 64;
        const float gi = gate_sB[ld];
        const float gf = gate_sB[nd + ld];
        const float gc = gate_sB[2*nd + ld];
        const float go = gate_sB[3*nd + ld];
        const float iv = sigmf(gi), fv = sigmf(gf), gv = tanhf(gc), ov = sigmf(go);
        const float cn = fv*c_sB[ld] + iv*gv;
        const float hn = ov*tanhf(cn);
        c_sB[ld] = cn;
        icst64(&h_sh[(p*NISL + batB)*Hq + d0 + ld], packtv((unsigned)(t+1), hn));
        if (t == Tq - 1){
          yout[Bq*Tq*OUTq + batB*Hq + d0 + ld] = hn;
          yout[Bq*Tq*OUTq + Bq*Hq + batB*Hq + d0 + ld] = cn;
        }
      }
      // restage h(t): thread-split (tid<256 island A 2 dims, else B 2 dims)
      if (tid < 256){
        const int i0 = 2*tid;
        inp_sA[64 + i0]     = waitword(&h_sh[(p*NISL + batA)*Hq + i0],     (unsigned)(t+1), fast);
        inp_sA[64 + i0 + 1] = waitword(&h_sh[(p*NISL + batA)*Hq + i0 + 1], (unsigned)(t+1), fast);
      } else {
        const int i0 = 2*(tid - 256);
        inp_sB[64 + i0]     = waitword(&h_sh[(p*NISL + batB)*Hq + i0],     (unsigned)(t+1), fast);
        inp_sB[64 + i0 + 1] = waitword(&h_sh[(p*NISL + batB)*Hq + i0 + 1], (unsigned)(t+1), fast);
      }
      if (t + 1 < Tq){
        if (tid < 16)
          *(float4*)&inp_sA[tid*4] = ((const float4*)xg)[(batA*Tq + t + 1)*16 + tid];
        else if (tid < 32)
          *(float4*)&inp_sB[(tid-16)*4] = ((const float4*)xg)[(batB*Tq + t + 1)*16 + (tid-16)];
      }
      __syncthreads();                 // S3
    }
  }
  else {
    // ---- mem WG: islands A,B — heads, softmax, update, r, out ----
    float* mem_sA = (float*)smem;               // 128 x 44
    float* mem_sB = (float*)(smem + 22528);     // 128 x 44
    float* h_sA   = (float*)(smem + 45056);     // 512
    float* h_sB   = (float*)(smem + 47104);     // 512
    float* hredA  = (float*)(smem + 49152);     // 128 x 4
    float* hredB  = (float*)(smem + 51200);     // 128 x 4
    float* keyA   = (float*)(smem + 53248);     // 40
    float* keyB   = (float*)(smem + 53408);     // 40
    float* eA     = (float*)(smem + 53568);     // 40
    float* eB     = (float*)(smem + 53728);     // 40
    float* aA     = (float*)(smem + 53888);     // 40
    float* aB     = (float*)(smem + 54048);     // 40
    float* w_sA   = (float*)(smem + 54208);     // 128
    float* w_sB   = (float*)(smem + 54720);     // 128
    float* rredA  = (float*)(smem + 55232);     // 40 x 9
    float* rredB  = (float*)(smem + 56672);     // 40 x 9
    float* oredA  = (float*)(smem + 58112);     // 64 x 9
    float* oredB  = (float*)(smem + 60416);     // 64 x 9

    #pragma unroll
    for (int q = 0; q < 10; ++q){
      const int e = q*512 + tid;
      const int n = e / 40, m = e - n*40;
      mem_sA[n*44 + m] = mem0g[batA*(Nq*Mq) + e];
      mem_sB[n*44 + m] = mem0g[batB*(Nq*Mq) + e];
    }
    const int o  = tid & 127;
    const int kc = tid >> 7;
    const float* wrow = (o < 40) ? (Wk + o*Hq)
                      : (o < 80) ? (We + (o-40)*Hq)
                      : (o < 120) ? (Wa + (o-80)*Hq)
                      : (o == 120) ? Wb : nullptr;
    float4 wv2[32];
    if (wrow){
      #pragma unroll
      for (int kk = 0; kk < 32; ++kk)
        wv2[kk] = *(const float4*)&wrow[kc*128 + kk*4];
    } else {
      #pragma unroll
      for (int kk = 0; kk < 32; ++kk) wv2[kk] = make_float4(0.f,0.f,0.f,0.f);
    }
    float4 wfc[16];
    {
      const int o2 = tid & 63, kc8 = tid >> 6;
      #pragma unroll
      for (int kk = 0; kk < 16; ++kk)
        wfc[kk] = *(const float4*)&Wfc[o2*Hq + kc8*64 + kk*4];
    }
    const float bfcv = bfc[tid & 63];
    float hb0 = 0.f, hb1 = 0.f;
    if (tid < 128){
      const int l = tid & 63;
      const int o1 = l + 64;
      hb0 = (l < 40) ? bk[l] : be[l-40];
      hb1 = (o1 < 80) ? be[o1-40] : (o1 < 120) ? ba[o1-80]
          : (o1 == 120) ? bbeta[0] : 0.f;
    }
    __syncthreads();
    if (tid == 0) s_fast = ready_and_handshake(rdy, magic, blk);
    __syncthreads();
    const bool fast = (s_fast != 0);

    for (int t = 0; t < Tq; ++t){
      const int p = t & 1;
      const unsigned want = (unsigned)(t + 1);
      // acquire h(t): thread-split parallel waits
      if (tid < 256){
        const int i0 = 2*tid;
        h_sA[i0]     = waitword(&h_sh[(p*NISL + batA)*Hq + i0],     want, fast);
        h_sA[i0 + 1] = waitword(&h_sh[(p*NISL + batA)*Hq + i0 + 1], want, fast);
      } else {
        const int i0 = 2*(tid - 256);
        h_sB[i0]     = waitword(&h_sh[(p*NISL + batB)*Hq + i0],     want, fast);
        h_sB[i0 + 1] = waitword(&h_sh[(p*NISL + batB)*Hq + i0 + 1], want, fast);
      }
      __syncthreads();                               // M1
      { // heads GEMV A then B (full WG, shared wv2)
        float a0 = 0.f;
        const float* hp = h_sA + kc*128;
        #pragma unroll
        for (int kk = 0; kk < 32; ++kk){
          const float4 f = *(const float4*)&hp[kk*4];
          a0 += wv2[kk].x*f.x + wv2[kk].y*f.y + wv2[kk].z*f.z + wv2[kk].w*f.w;
        }
        hredA[o*4 + kc] = a0;
        float b0 = 0.f;
        const float* hq = h_sB + kc*128;
        #pragma unroll
        for (int kk = 0; kk < 32; ++kk){
          const float4 f = *(const float4*)&hq[kk*4];
          b0 += wv2[kk].x*f.x + wv2[kk].y*f.y + wv2[kk].z*f.z + wv2[kk].w*f.w;
        }
        hredB[o*4 + kc] = b0;
      }
      __syncthreads();                               // M2
      if (tid < 128){ // serial sections: wave0 = A, wave1 = B (parallel)
        const int l = tid & 63;
        float* hred = (tid < 64) ? hredA : hredB;
        float* key_s= (tid < 64) ? keyA  : keyB;
        float* e_s  = (tid < 64) ? eA    : eB;
        float* a_s  = (tid < 64) ? aA    : aB;
        float* w_s  = (tid < 64) ? w_sA  : w_sB;
        float* mem_s= (tid < 64) ? mem_sA: mem_sB;
        const float4 p0 = *(const float4*)&hred[l*4];
        const float4 p1 = *(const float4*)&hred[(l+64)*4];
        float s0 = hb0 + p0.x + p0.y + p0.z + p0.w;
        float s1 = hb1 + p1.x + p1.y + p1.z + p1.w;
        float kv = 0.f;
        if (l < 40){ kv = tanhf(s0); key_s[l] = kv; }
        else        { e_s[l-40] = sigmf(s0); }
        if (l < 16)      e_s[l+24]  = sigmf(s1);     // o1 in [64,80)
        else if (l < 56) a_s[l-16]  = tanhf(s1);     // o1 in [80,120)
        float bval = softplusf(s1) + EPSq;           // lane 56: o1==120
        const float bet = __shfl(bval, 56);
        float ss = kv*kv;
        #pragma unroll
        for (int off = 32; off; off >>= 1) ss += __shfl_xor(ss, off);
        const float rinv = 1.f/(sqrtf(ss) + EPSq);
        float sc[2];
        #pragma unroll
        for (int half = 0; half < 2; ++half){
          const int n = l + 64*half;
          float qq = 0.f, dd = 0.f;
          const float* mrow = &mem_s[n*44];
          #pragma unroll
          for (int q = 0; q < 10; ++q){
            const float4 mv = *(const float4*)&mrow[q*4];
            const float4 kvv = *(const float4*)&key_s[q*4];
            qq += mv.x*mv.x + mv.y*mv.y + mv.z*mv.z + mv.w*mv.w;
            dd += mv.x*kvv.x + mv.y*kvv.y + mv.z*kvv.z + mv.w*kvv.w;
          }
          sc[half] = bet * dd * rinv / (sqrtf(qq) + EPSq);
        }
        // softmax without max-subtraction: |beta*sim| <= ~8.3 -> fp32-safe
        // (validated: absmax identical to max-shifted form)
        const float e0 = expf(sc[0]), e1 = expf(sc[1]);
        float sm = e0 + e1;
        #pragma unroll
        for (int off = 32; off; off >>= 1) sm += __shfl_xor(sm, off);
        const float inv = 1.f/sm;
        w_s[l] = e0*inv; w_s[l+64] = e1*inv;
      }
      __syncthreads();                               // M3
      if (tid < 320){ // fused erase/add update + read partials, A then B
        const int m = tid % 40, ng = tid / 40;
        {
          const float ev = eA[m], av = aA[m];
          float part = 0.f;
          #pragma unroll
          for (int q = 0; q < 16; ++q){
            const int n = ng*16 + q, idx2 = n*44 + m;
            const float mv = mem_sA[idx2];
            const float wn = w_sA[n];
            const float nv = fmaf(wn, fmaf(-ev, mv, av), mv);
            mem_sA[idx2] = nv;
            part = fmaf(wn, nv, part);
          }
          rredA[m*9 + ng] = part;
        }
        {
          const float ev = eB[m], av = aB[m];
          float part = 0.f;
          #pragma unroll
          for (int q = 0; q < 16; ++q){
            const int n = ng*16 + q, idx2 = n*44 + m;
            const float mv = mem_sB[idx2];
            const float wn = w_sB[n];
            const float nv = fmaf(wn, fmaf(-ev, mv, av), mv);
            mem_sB[idx2] = nv;
            part = fmaf(wn, nv, part);
          }
          rredB[m*9 + ng] = part;
        }
      }
      __syncthreads();                               // M4
      // r publish: A lanes 0..39, B lanes 64..103 (parallel)
      if (tid < 40){
        float r = 0.f;
        #pragma unroll
        for (int q = 0; q < 8; ++q) r += rredA[tid*9 + q];
        icst64(&r_sh[(p*NISL + batA)*Mq + tid], packtv(want, r));
      } else if (tid >= 64 && tid < 104){
        const int ld = tid - 64;
        float r = 0.f;
        #pragma unroll
        for (int q = 0; q < 8; ++q) r += rredB[ld*9 + q];
        icst64(&r_sh[(p*NISL + batB)*Mq + ld], packtv(want, r));
      }
      { // out(t) GEMV A then B (full WG, shared wfc) — off critical path
        const int o2 = tid & 63, kc8 = tid >> 6;
        float a0 = 0.f;
        const float* hp = h_sA + kc8*64;
        #pragma unroll
        for (int kk = 0; kk < 16; ++kk){
          const float4 f = *(const float4*)&hp[kk*4];
          a0 += wfc[kk].x*f.x + wfc[kk].y*f.y + wfc[kk].z*f.z + wfc[kk].w*f.w;
        }
        oredA[o2*9 + kc8] = a0;
        float b0 = 0.f;
        const float* hq = h_sB + kc8*64;
        #pragma unroll
        for (int kk = 0; kk < 16; ++kk){
          const float4 f = *(const float4*)&hq[kk*4];
          b0 += wfc[kk].x*f.x + wfc[kk].y*f.y + wfc[kk].z*f.z + wfc[kk].w*f.w;
        }
        oredB[o2*9 + kc8] = b0;
      }
      __syncthreads();                               // M5
      if (tid < 128){ // final out sums: wave0 = A, wave1 = B
        const int l = tid & 63;
        const float* op = (tid < 64) ? &oredA[l*9] : &oredB[l*9];
        const int bat = (tid < 64) ? batA : batB;
        float s2 = bfcv;
        #pragma unroll
        for (int q = 0; q < 8; ++q) s2 += op[q];
        yout[(bat*Tq + t)*OUTq + l] = tanhf(s2);
      }
      __syncthreads();                               // M6: h_s reuse guard
    }
  }
}

extern "C" void kernel_launch(void* const* d_in, const int* in_sizes, int n_in,
                              void* d_out, int out_size, void* d_ws, size_t ws_size,
                              hipStream_t stream){
  const float* xg    = (const float*)d_in[0];
  const float* h0g   = (const float*)d_in[1];
  const float* c0g   = (const float*)d_in[2];
  const float* mem0g = (const float*)d_in[3];
  const float* read0g= (const float*)d_in[4];
  const float* Wih   = (const float*)d_in[5];
  const float* bih   = (const float*)d_in[6];
  const float* Whh   = (const float*)d_in[7];
  const float* bhh   = (const float*)d_in[8];
  const float* Wfc   = (const float*)d_in[9];
  const float* bfc   = (const float*)d_in[10];
  const float* We    = (const float*)d_in[11];
  const float* be    = (const float*)d_in[12];
  const float* Wa    = (const float*)d_in[13];
  const float* ba    = (const float*)d_in[14];
  const float* Wk    = (const float*)d_in[15];
  const float* bk    = (const float*)d_in[16];
  const float* Wb    = (const float*)d_in[17];
  const float* bbeta = (const float*)d_in[18];

  float* yout  = (float*)d_out;
  ull*   rdy   = (ull*)d_ws;                         // word 0; word 1 = magic
  ull*   h_sh  = (ull*)((char*)d_ws + 4096);         // 2x16x512 = 16384 ull
  ull*   r_sh  = (ull*)((char*)d_ws + 135168);       // 2x16x40 = 1280 ull

  hipMemsetAsync(d_ws, 0, 147456, stream);           // tags=0 != any want (1..1024)
  hipLaunchKernelGGL(ntm_kernel, dim3(NWG), dim3(NT), 0, stream,
                     xg, h0g, c0g, mem0g, read0g, Wih, bih, Whh, bhh,
                     Wfc, bfc, We, be, Wa, ba, Wk, bk, Wb, bbeta,
                     yout, rdy, h_sh, r_sh);
}

// Round 11
// 7354.158 us; speedup vs baseline: 1.4407x; 1.4407x over previous
//
#include <hip/hip_runtime.h>
#include <math.h>

#define Bq   16
#define Tq   1024
#define OUTq 64
#define Hq   512
#define Nq   128
#define Mq   40
#define NT   512
#define NISL 16        // islands = batches
#define GWG  13        // gate WGs per island (12 x 40 dims + 1 x 32 dims)
#define IWG  14        // WGs per island (GWG + 1 mem)
#define NWG  224
#define EPSq 1e-8f
#define MAGIC 0x00C0FFEEu

typedef unsigned long long ull;

__device__ __forceinline__ float sigmf(float x){ return 1.f/(1.f + expf(-x)); }
__device__ __forceinline__ float softplusf(float x){ return (x > 20.f) ? x : log1pf(expf(x)); }

// Agent-scope atomic ops: authoritative cross-XCD path.
__device__ __forceinline__ ull icld64(const ull* p){
  return __hip_atomic_load(p, __ATOMIC_RELAXED, __HIP_MEMORY_SCOPE_AGENT);
}
__device__ __forceinline__ void icst64(ull* p, ull v){
  __hip_atomic_store(p, v, __ATOMIC_RELAXED, __HIP_MEMORY_SCOPE_AGENT);
}
// IC poll load: sc0 bypasses L1, sc1 bypasses L2 -> reads the coherence point
// like the agent atomic load, but as a PLAIN coalescing load.
__device__ __forceinline__ ull icpoll64(const ull* p){
  ull v;
  asm volatile("global_load_dwordx2 %0, %1, off sc0 sc1\n\ts_waitcnt vmcnt(0)"
               : "=v"(v) : "v"(p) : "memory");
  return v;
}
__device__ __forceinline__ ull packtv(unsigned tag, float v){
  return ((ull)tag << 32) | (ull)__float_as_uint(v);
}
__device__ __forceinline__ float lowf(ull v){ return __uint_as_float((unsigned)v); }

// Tag-verified wait (tag+payload one atomic 8B word, tags monotone, parity-2
// slot reuse guarded by the dependency chain). `fast` enabled only after the
// runtime handshake proved sc0sc1 loads observe agent stores; bounded with an
// agent-loop tail so no configuration can hang.
__device__ __forceinline__ float waitword(const ull* sh, unsigned want, bool fast){
  if (fast){
    #pragma unroll 1
    for (int i = 0; i < 4096; ++i){
      const ull v = icpoll64(sh);
      if ((unsigned)(v >> 32) == want) return lowf(v);
      __builtin_amdgcn_s_sleep(1);
    }
  }
  #pragma unroll 1
  for (;;){
    const ull v = icld64(sh);
    if ((unsigned)(v >> 32) == want) return lowf(v);
    __builtin_amdgcn_s_sleep(1);
  }
}

__device__ __forceinline__ int ready_and_handshake(ull* rdy, ull* magic, int blk){
  __hip_atomic_fetch_add(rdy, 1ull, __ATOMIC_RELAXED, __HIP_MEMORY_SCOPE_AGENT);
  while (icld64(rdy) < (ull)NWG) __builtin_amdgcn_s_sleep(8);
  if (blk == 0) icst64(magic, ((ull)MAGIC << 32) | 1ull);
  #pragma unroll 1
  for (int i = 0; i < 4000; ++i){
    if ((unsigned)(icpoll64(magic) >> 32) == MAGIC) return 1;
    __builtin_amdgcn_s_sleep(2);
  }
  return 0;
}

// r11 = r4 + head-row offload. The mem WG's 121x512 heads GEMV streamed
// ~250KB/step of L2-resident weights ON the critical chain (FETCH-invisible;
// the ~1.8us gap in the cycle model). Gate WGs already restage full h(t+1)
// every step — each now computes its 10 COMPLETE head rows (weights in +20KB
// static LDS) right after the restage and publishes 121 tagged words/island
// (tags 1..Tq, published unconditionally at end of EVERY iter => the mem WG's
// last wait is always satisfiable). Mem's critical phase shrinks to:
// wait 121 words -> serial softmax -> update -> r publish.
extern "C" __global__ void __launch_bounds__(NT, 1)
ntm_kernel(const float* __restrict__ xg,  const float* __restrict__ h0g,
           const float* __restrict__ c0g, const float* __restrict__ mem0g,
           const float* __restrict__ read0g,
           const float* __restrict__ Wih, const float* __restrict__ bih,
           const float* __restrict__ Whh, const float* __restrict__ bhh,
           const float* __restrict__ Wfc, const float* __restrict__ bfc,
           const float* __restrict__ We,  const float* __restrict__ be,
           const float* __restrict__ Wa,  const float* __restrict__ ba,
           const float* __restrict__ Wk,  const float* __restrict__ bk,
           const float* __restrict__ Wb,  const float* __restrict__ bbeta,
           float* __restrict__ yout, ull* __restrict__ rdy,
           ull* __restrict__ h_sh, ull* __restrict__ r_sh,
           ull* __restrict__ hp_sh)
{
  const int blk = blockIdx.x;
  const int tid = threadIdx.x;
  const int x   = blk & 7;
  const int j   = blk >> 3;
  const int bat = (j < IWG) ? x : (x + 8);
  const int slot= (j < IWG) ? j : (j - IWG);
  __shared__ __align__(16) char smem[61760];
  __shared__ int s_fast;
  ull* magic = rdy + 1;

  if (slot < GWG){
    // ---- gate WG: island `bat`, h-dims [d0, d0+nd) + 10 head rows ----
    float* inp_s  = (float*)smem;               // 640 f: x[0,64) h[64,576)
    float* red_s  = (float*)(smem + 2560);      // 160 x 17
    float* rw_s   = (float*)(smem + 13440);     // 160 x 41 (r-slice weights)
    float* hw_s   = (float*)(smem + 39680);     // 10 x 512 head-row weights
    float* r_s    = (float*)(smem + 60160);     // 40
    float* gate_s = (float*)(smem + 60320);     // 160
    float* c_s    = (float*)(smem + 60960);     // 40
    float* bias_s = (float*)(smem + 61120);     // 160

    const int kseg  = tid & 15;       // 36-float k-slice of 576 (x|h)
    const int rslot = tid >> 4;       // 32 row-slots x 5 rows (padded)
    const int nd    = (slot < 12) ? 40 : 32;
    const int d0    = slot * 40;
    const int rowsR = 4 * nd;         // 160 or 128 real rows

    float4 w4[5][9];
    #pragma unroll
    for (int rr = 0; rr < 5; ++rr){
      const int row = rslot*5 + rr;
      if (row < rowsR){
        const int gate = row / nd, ld = row - gate*nd;
        const int grow = gate*Hq + d0 + ld;
        #pragma unroll
        for (int kk = 0; kk < 9; ++kk){
          float v[4];
          #pragma unroll
          for (int c4 = 0; c4 < 4; ++c4){
            const int k = kseg*36 + kk*4 + c4;
            v[c4] = (k < 64) ? Wih[grow*104 + k] : Whh[grow*512 + (k - 64)];
          }
          w4[rr][kk] = make_float4(v[0], v[1], v[2], v[3]);
        }
      } else {
        #pragma unroll
        for (int kk = 0; kk < 9; ++kk) w4[rr][kk] = make_float4(0.f,0.f,0.f,0.f);
      }
    }
    if (tid < rowsR){
      const int gate = tid / nd, ld = tid - gate*nd;
      const int grow = gate*Hq + d0 + ld;
      bias_s[tid] = bih[grow] + bhh[grow];
    }
    for (int i = tid; i < rowsR*40; i += NT){
      const int row = i / 40, m = i - row*40;
      const int gate = row / nd, ld = row - gate*nd;
      const int grow = gate*Hq + d0 + ld;
      rw_s[row*41 + m] = Wih[grow*104 + 64 + m];
    }
    // head-row weight slices: this WG owns rows slot*10 .. slot*10+9 (<121)
    for (int i = tid; i < 10*512; i += NT){
      const int lr = i >> 9, d = i & 511;
      const int grow = slot*10 + lr;
      float v = 0.f;
      if (grow < 121){
        v = (grow < 40) ? Wk[grow*Hq + d]
          : (grow < 80) ? We[(grow-40)*Hq + d]
          : (grow < 120) ? Wa[(grow-80)*Hq + d] : Wb[d];
      }
      hw_s[i] = v;
    }
    if (tid < nd) c_s[tid] = c0g[bat*Hq + d0 + tid];
    if (tid < 16)
      *(float4*)&inp_s[tid*4] = ((const float4*)xg)[(bat*Tq + 0)*16 + tid];
    if (tid < 128)
      *(float4*)&inp_s[64 + tid*4] = ((const float4*)h0g)[bat*128 + tid];
    __syncthreads();
    if (tid == 0) s_fast = ready_and_handshake(rdy, magic, blk);
    __syncthreads();
    const bool fast = (s_fast != 0);

    for (int t = 0; t < Tq; ++t){
      const int p = t & 1, pm = (t - 1) & 1;
      // main GEMV over x+h (576) — overlaps the island's mem phase
      float acc[5] = {0.f,0.f,0.f,0.f,0.f};
      {
        const float* bp = inp_s + kseg*36;
        #pragma unroll
        for (int kk = 0; kk < 9; ++kk){
          const float4 f = *(const float4*)&bp[kk*4];
          #pragma unroll
          for (int rr = 0; rr < 5; ++rr)
            acc[rr] += w4[rr][kk].x*f.x + w4[rr][kk].y*f.y
                     + w4[rr][kk].z*f.z + w4[rr][kk].w*f.w;
        }
      }
      #pragma unroll
      for (int rr = 0; rr < 5; ++rr)
        red_s[(rslot*5 + rr)*17 + kseg] = acc[rr];
      // r(t-1): island hop (t=0: pristine input)
      if (t == 0){
        if (tid < 40) r_s[tid] = read0g[bat*Mq + tid];
      } else if (tid < 40){
        const int idx = (pm*NISL + bat)*Mq + tid;
        r_s[tid] = waitword(&r_sh[idx], (unsigned)t, fast);
      }
      __syncthreads();                 // S1
      if (tid < rowsR){
        float s2 = bias_s[tid];
        const float* rp = &red_s[tid*17];
        #pragma unroll
        for (int q = 0; q < 16; ++q) s2 += rp[q];
        const float* rwp = &rw_s[tid*41];
        #pragma unroll
        for (int m = 0; m < 40; ++m) s2 += rwp[m]*r_s[m];
        gate_s[tid] = s2;
      }
      __syncthreads();                 // S2
      if (tid < nd){
        const float gi = gate_s[tid];
        const float gf = gate_s[nd + tid];
        const float gc = gate_s[2*nd + tid];
        const float go = gate_s[3*nd + tid];
        const float iv = sigmf(gi), fv = sigmf(gf), gv = tanhf(gc), ov = sigmf(go);
        const float cn = fv*c_s[tid] + iv*gv;
        const float hn = ov*tanhf(cn);
        c_s[tid] = cn;
        const int idx = (p*NISL + bat)*Hq + d0 + tid;
        icst64(&h_sh[idx], packtv((unsigned)(t+1), hn));
        if (t == Tq - 1){
          yout[Bq*Tq*OUTq + bat*Hq + d0 + tid] = hn;             // final h
          yout[Bq*Tq*OUTq + Bq*Hq + bat*Hq + d0 + tid] = cn;     // final c
        }
      }
      // stage full h(t+1): one dim per thread (unguarded — also feeds the
      // final heads publish at t = Tq-1)
      {
        const int idx = (p*NISL + bat)*Hq + tid;
        inp_s[64 + tid] = waitword(&h_sh[idx], (unsigned)(t+1), fast);
      }
      if (t + 1 < Tq && tid < 16)
        *(float4*)&inp_s[tid*4] = ((const float4*)xg)[(bat*Tq + t + 1)*16 + tid];
      __syncthreads();                 // S3: inp_s ready
      // head rows tag t+1 from restaged h: 10 rows x 32 lanes x 16 dims
      if (tid < 320){
        const int grp = tid >> 5, ln = tid & 31;
        const int grow = slot*10 + grp;
        if (grow < 121){
          const float* wp  = &hw_s[grp*512 + ln*16];
          const float* hp2 = &inp_s[64 + ln*16];
          float ps = 0.f;
          #pragma unroll
          for (int q = 0; q < 4; ++q){
            const float4 wv = *(const float4*)&wp[q*4];
            const float4 hv = *(const float4*)&hp2[q*4];
            ps += wv.x*hv.x + wv.y*hv.y + wv.z*hv.z + wv.w*hv.w;
          }
          #pragma unroll
          for (int off = 16; off; off >>= 1) ps += __shfl_xor(ps, off);
          if (ln == 0)
            icst64(&hp_sh[(p*NISL + bat)*128 + grow], packtv((unsigned)(t+1), ps));
        }
      }
    }
  }
  else {
    // ---- mem WG: island `bat` — serial softmax, memory update, r, out ----
    float* mem_s  = (float*)smem;               // 128 x 44
    float* h_s    = (float*)(smem + 22528);     // 512
    float* hred_s = (float*)(smem + 24576);     // 128 raw head dots
    float* key_s  = (float*)(smem + 25088);     // 40
    float* e_s    = (float*)(smem + 25248);     // 40
    float* a_s    = (float*)(smem + 25408);     // 40
    float* w_s    = (float*)(smem + 25568);     // 128
    float* rred_s = (float*)(smem + 26080);     // 40 x 9
    float* ored_s = (float*)(smem + 27520);     // 64 x 9

    #pragma unroll
    for (int q = 0; q < 10; ++q){
      const int e = q*512 + tid;
      const int n = e / 40, m = e - n*40;
      mem_s[n*44 + m] = mem0g[bat*(Nq*Mq) + e];
    }
    if (tid < 128) hred_s[tid] = 0.f;           // rows 121..127 stay 0
    float4 wfc[16];
    {
      const int o2 = tid & 63, kc8 = tid >> 6;
      #pragma unroll
      for (int kk = 0; kk < 16; ++kk)
        wfc[kk] = *(const float4*)&Wfc[o2*Hq + kc8*64 + kk*4];
    }
    const float bfcv = bfc[tid & 63];
    float hb0 = 0.f, hb1 = 0.f;
    if (tid < 64){
      const int o0 = tid, o1 = tid + 64;
      hb0 = (o0 < 40) ? bk[o0] : be[o0-40];
      hb1 = (o1 < 80) ? be[o1-40] : (o1 < 120) ? ba[o1-80]
          : (o1 == 120) ? bbeta[0] : 0.f;
    }
    __syncthreads();
    if (tid == 0) s_fast = ready_and_handshake(rdy, magic, blk);
    __syncthreads();
    const bool fast = (s_fast != 0);

    for (int t = 0; t < Tq; ++t){
      const int p = t & 1;
      const unsigned want = (unsigned)(t + 1);
      // acquire the 121 head dots (published by gate WGs post-restage)
      if (tid < 121)
        hred_s[tid] = waitword(&hp_sh[(p*NISL + bat)*128 + tid], want, fast);
      __syncthreads();                               // M2
      if (tid < 64){ // wave 0: serial section, shuffle-reduced
        const int l = tid;
        float s0 = hb0 + hred_s[l];
        float s1 = hb1 + hred_s[64 + l];
        float kv = 0.f;
        if (l < 40){ kv = tanhf(s0); key_s[l] = kv; }
        else        { e_s[l-40] = sigmf(s0); }
        if (l < 16)      e_s[l+24]  = sigmf(s1);     // rows 64..79
        else if (l < 56) a_s[l-16]  = tanhf(s1);     // rows 80..119
        float bval = softplusf(s1) + EPSq;           // lane 56: row 120
        const float bet = __shfl(bval, 56);
        float ss = kv*kv;
        #pragma unroll
        for (int off = 32; off; off >>= 1) ss += __shfl_xor(ss, off);
        const float rinv = 1.f/(sqrtf(ss) + EPSq);
        float sc[2];
        #pragma unroll
        for (int half = 0; half < 2; ++half){
          const int n = l + 64*half;
          float qq = 0.f, dd = 0.f;
          const float* mrow = &mem_s[n*44];
          #pragma unroll
          for (int q = 0; q < 10; ++q){
            const float4 mv = *(const float4*)&mrow[q*4];
            const float4 kvv = *(const float4*)&key_s[q*4];
            qq += mv.x*mv.x + mv.y*mv.y + mv.z*mv.z + mv.w*mv.w;
            dd += mv.x*kvv.x + mv.y*kvv.y + mv.z*kvv.z + mv.w*kvv.w;
          }
          sc[half] = bet * dd * rinv / (sqrtf(qq) + EPSq);
        }
        // softmax without max-subtraction: |beta*sim| <= ~8.3 -> fp32-safe
        // (validated: absmax identical to max-shifted form)
        const float e0 = expf(sc[0]), e1 = expf(sc[1]);
        float sm = e0 + e1;
        #pragma unroll
        for (int off = 32; off; off >>= 1) sm += __shfl_xor(sm, off);
        const float inv = 1.f/sm;
        w_s[l] = e0*inv; w_s[l+64] = e1*inv;
      }
      __syncthreads();                               // M3
      if (tid < 320){ // fused erase/add update + read partials
        const int m = tid % 40, ng = tid / 40;
        const float ev = e_s[m], av = a_s[m];
        float part = 0.f;
        #pragma unroll
        for (int q = 0; q < 16; ++q){
          const int n = ng*16 + q, idx2 = n*44 + m;
          const float mv = mem_s[idx2];
          const float wn = w_s[n];
          const float nv = fmaf(wn, fmaf(-ev, mv, av), mv);
          mem_s[idx2] = nv;
          part = fmaf(wn, nv, part);
        }
        rred_s[m*9 + ng] = part;
      }
      __syncthreads();                               // M4
      if (tid < 40){
        float r = 0.f;
        #pragma unroll
        for (int q = 0; q < 8; ++q) r += rred_s[tid*9 + q];
        const int idx = (p*NISL + bat)*Mq + tid;
        icst64(&r_sh[idx], packtv(want, r));
      }
      { // h(t+1) for out-GEMV: published long ago -> near-zero wait
        const int idx = (p*NISL + bat)*Hq + tid;
        h_s[tid] = waitword(&h_sh[idx], want, fast);
      }
      __syncthreads();                               // M5a
      { // out(t) = tanh(Wfc h + bfc): off critical path
        const int o2 = tid & 63, kc8 = tid >> 6;
        float a0 = 0.f;
        const float* hp = h_s + kc8*64;
        #pragma unroll
        for (int kk = 0; kk < 16; ++kk){
          const float4 f = *(const float4*)&hp[kk*4];
          a0 += wfc[kk].x*f.x + wfc[kk].y*f.y + wfc[kk].z*f.z + wfc[kk].w*f.w;
        }
        ored_s[o2*9 + kc8] = a0;
      }
      __syncthreads();                               // M5b
      if (tid < 64){
        float s2 = bfcv;
        const float* op = &ored_s[tid*9];
        #pragma unroll
        for (int q = 0; q < 8; ++q) s2 += op[q];
        yout[(bat*Tq + t)*OUTq + tid] = tanhf(s2);
      }
      __syncthreads();                               // M6: h_s/hred reuse guard
    }
  }
}

extern "C" void kernel_launch(void* const* d_in, const int* in_sizes, int n_in,
                              void* d_out, int out_size, void* d_ws, size_t ws_size,
                              hipStream_t stream){
  const float* xg    = (const float*)d_in[0];
  const float* h0g   = (const float*)d_in[1];
  const float* c0g   = (const float*)d_in[2];
  const float* mem0g = (const float*)d_in[3];
  const float* read0g= (const float*)d_in[4];
  const float* Wih   = (const float*)d_in[5];
  const float* bih   = (const float*)d_in[6];
  const float* Whh   = (const float*)d_in[7];
  const float* bhh   = (const float*)d_in[8];
  const float* Wfc   = (const float*)d_in[9];
  const float* bfc   = (const float*)d_in[10];
  const float* We    = (const float*)d_in[11];
  const float* be    = (const float*)d_in[12];
  const float* Wa    = (const float*)d_in[13];
  const float* ba    = (const float*)d_in[14];
  const float* Wk    = (const float*)d_in[15];
  const float* bk    = (const float*)d_in[16];
  const float* Wb    = (const float*)d_in[17];
  const float* bbeta = (const float*)d_in[18];

  float* yout  = (float*)d_out;
  ull*   rdy   = (ull*)d_ws;                         // word 0; word 1 = magic
  ull*   h_sh  = (ull*)((char*)d_ws + 4096);         // 2x16x512 = 16384 ull
  ull*   r_sh  = (ull*)((char*)d_ws + 135168);       // 2x16x40 = 1280 ull
  ull*   hp_sh = (ull*)((char*)d_ws + 147456);       // 2x16x128 = 4096 ull

  hipMemsetAsync(d_ws, 0, 180224, stream);           // tags=0 != any want (1..1024)
  hipLaunchKernelGGL(ntm_kernel, dim3(NWG), dim3(NT), 0, stream,
                     xg, h0g, c0g, mem0g, read0g, Wih, bih, Whh, bhh,
                     Wfc, bfc, We, be, Wa, ba, Wk, bk, Wb, bbeta,
                     yout, rdy, h_sh, r_sh, hp_sh);
}